// Round 13
// baseline (926.986 us; speedup 1.0000x reference)
//
#include <hip/hip_runtime.h>
#include <hip/hip_bf16.h>
#include <math.h>

// Problem constants
#define E_ 8
#define D_ 2048
#define I_ 4096
#define TOPK_ 2
#define N_ 4096
#define NPAIR (N_*TOPK_)
#define PADMAX 10240
#define MAXTB 40
#define CVTX 24          // fine-grained wd-converter bx columns in gu kernel
#define CH_X   (1L<<20)  // x chunks (8 elems each)
#define CH_FULL (1L<<23) // full [E][I][D] matrix chunks
#define CH_WD  (1L<<23)

typedef __attribute__((ext_vector_type(8))) short s8v;
typedef __attribute__((ext_vector_type(8))) unsigned short us8;
typedef __attribute__((ext_vector_type(4))) float f32x4;
typedef const __attribute__((address_space(1))) void* gvp;
typedef __attribute__((address_space(3))) void* lvp;

__device__ __forceinline__ unsigned short f2bf(float f) {
  union { float f; unsigned int u; } c; c.f = f;
  unsigned int u = c.u;
  u += 0x7fffu + ((u >> 16) & 1u);
  return (unsigned short)(u >> 16);
}

__device__ __forceinline__ void cvt_chunk(const float* __restrict__ src,
                                          unsigned short* __restrict__ dst,
                                          size_t off) {
  float4 a = *(const float4*)(src + off);
  float4 b = *(const float4*)(src + off + 4);
  us8 o;
  o[0]=f2bf(a.x); o[1]=f2bf(a.y); o[2]=f2bf(a.z); o[3]=f2bf(a.w);
  o[4]=f2bf(b.x); o[5]=f2bf(b.y); o[6]=f2bf(b.z); o[7]=f2bf(b.w);
  *(us8*)(dst + off) = o;
}

// ---------------- Head: route (block 0) + x cvt + FULL wg/wu cvt ----------------
__global__ __launch_bounds__(512)
void head_kernel(const int* __restrict__ idx, const float* __restrict__ ew,
                 int* cnt, int* offs, int* tb, int* ntb,
                 int* perm, float* wgt,
                 const float* __restrict__ x, unsigned short* __restrict__ xb,
                 const float* __restrict__ wg, unsigned short* __restrict__ wgb,
                 const float* __restrict__ wu, unsigned short* __restrict__ wub)
{
  if (blockIdx.x == 0) {
    __shared__ int scnt[E_], soff[E_ + 1], scur[E_];
    int t = threadIdx.x;
    if (t < E_) scnt[t] = 0;
    __syncthreads();
    for (int p = t; p < NPAIR; p += blockDim.x) atomicAdd(&scnt[idx[p]], 1);
    __syncthreads();
    if (t == 0) {
      int o = 0;
      for (int e = 0; e < E_; e++) {
        soff[e] = o; scur[e] = o;
        o += ((scnt[e] + 255) / 256) * 256;
      }
      soff[E_] = o;
      int T = 0;
      for (int e = 0; e < E_; e++) {
        int nb = (scnt[e] + 255) / 256;
        for (int rb = 0; rb < nb; rb++) tb[T++] = (e << 16) | rb;
      }
      *ntb = T;
      for (int e = 0; e < E_; e++) { cnt[e] = scnt[e]; offs[e] = soff[e]; }
      offs[E_] = o;
    }
    __syncthreads();
    for (int e = 0; e < E_; e++) {
      int start = soff[e] + scnt[e], end = soff[e + 1];
      for (int s = start + t; s < end; s += blockDim.x) { perm[s] = -1; wgt[s] = 0.f; }
    }
    __syncthreads();
    for (int p = t; p < NPAIR; p += blockDim.x) {
      int e = idx[p];
      int pos = atomicAdd(&scur[e], 1);
      perm[pos] = p / TOPK_;
      wgt[pos]  = ew[p];
    }
    return;
  }
  const long TOTAL = CH_X + 2 * CH_FULL;
  long c0 = (long)(blockIdx.x - 1) * 512 + threadIdx.x;
  long stride = (long)(gridDim.x - 1) * 512;
  for (long c = c0; c < TOTAL; c += stride) {
    if (c < CH_X) cvt_chunk(x, xb, (size_t)c << 3);
    else if (c < CH_X + CH_FULL) cvt_chunk(wg, wgb, (size_t)(c - CH_X) << 3);
    else cvt_chunk(wu, wub, (size_t)(c - CH_X - CH_FULL) << 3);
  }
}

// =================== BK=32, 16-wave, 64 KB LDS, double-buffered GEMM (r12 proven) ===================
// Slab layout = round-3 proven (0 conflicts): [128 vrow][64 ushort]; vrow v packs
// rows 2v,2v+1; chunk c=(r&1)*4+kc at position p = c ^ (v&7). Stage: wave w ->
// vrows w*8..w*8+7 (dest w*512); source row = w*16+rrS, k = kcS with
// cS=(lane&7)^(lane>>3), rrS=2*(lane>>3)+(cS>>2), kcS=(cS&3)*8. Read:
// hl=(lane&15)>>1, pA=(((lane&1)*4+(lane>>4))^hl)*8, off = base + m*512 + hl*64 + pA.
// Pipeline: dbuf, VMW(2) before start-barrier (VMW(0) last), STG(t+2) after
// end-barrier; raw s_barrier only.

#define SB  __builtin_amdgcn_sched_barrier(0)
#define BARR __builtin_amdgcn_s_barrier()
#define VMW(N) asm volatile("s_waitcnt vmcnt(" #N ")" ::: "memory")
#define PRIO1 __builtin_amdgcn_s_setprio(1)
#define PRIO0 __builtin_amdgcn_s_setprio(0)

#define STG(T,P) { \
  __builtin_amdgcn_global_load_lds((gvp)(aptr + (size_t)(T)*32), (lvp)(&smem[(P)*8192 + w*512]), 16, 0, 0); \
  __builtin_amdgcn_global_load_lds((gvp)(bptr + (size_t)(T)*32), (lvp)(&smem[16384 + (P)*8192 + w*512]), 16, 0, 0); }

#define TILE32(T,P,NT_) { \
  if ((T) == (NT_)-1) { VMW(0); } else { VMW(2); } \
  SB; BARR; SB; \
  { const unsigned short* ap_ = &smem[(P)*8192 + aOff]; \
    const unsigned short* bp_ = &smem[16384 + (P)*8192 + bOff]; \
    s8v af[4], bf[4]; \
    af[0]=*(const s8v*)(ap_);      af[1]=*(const s8v*)(ap_+512); \
    af[2]=*(const s8v*)(ap_+1024); af[3]=*(const s8v*)(ap_+1536); \
    bf[0]=*(const s8v*)(bp_);      bf[1]=*(const s8v*)(bp_+512); \
    bf[2]=*(const s8v*)(bp_+1024); bf[3]=*(const s8v*)(bp_+1536); \
    PRIO1; \
    _Pragma("unroll") for (int m_=0;m_<4;m_++) \
      _Pragma("unroll") for (int n_=0;n_<4;n_++) \
        acc[m_][n_] = __builtin_amdgcn_mfma_f32_16x16x32_bf16(af[m_], bf[n_], acc[m_][n_], 0,0,0); \
    PRIO0; } \
  SB; BARR; SB; \
  if ((T)+2 < (NT_)) { STG((T)+2, P); } }

#define KLOOP32(NT_) { \
  STG(0,0); STG(1,1); \
  _Pragma("unroll 1") for (int tt=0; tt<(NT_)/2; ++tt) { \
    TILE32(2*tt,   0, NT_); \
    TILE32(2*tt+1, 1, NT_); } }

// ---------------- gate+up merged full-I: 256 tokens x 256 vcols, 32 by-cols ----------------
// GEMM blocks bx<40 (by 0..31 covers full I); converter blocks bx>=40 convert wd
// in fine grains (768 blocks x ~0.5 MB) that backfill scheduling gaps.
__global__ __launch_bounds__(1024, 4)
void gu32_kernel(const unsigned short* __restrict__ xb,
                 const unsigned short* __restrict__ wgb,
                 const unsigned short* __restrict__ wub,
                 const int* __restrict__ tb, const int* __restrict__ ntb,
                 const int* __restrict__ offs, const int* __restrict__ perm,
                 unsigned short* __restrict__ H,
                 const float* __restrict__ wd, unsigned short* __restrict__ wdb)
{
  __shared__ unsigned short smem[32768];   // 64 KB

  int tid = threadIdx.x;
  if (blockIdx.x >= MAXTB) {
    long cid = (long)(blockIdx.x - MAXTB) + (long)CVTX * blockIdx.y;
    long c0 = cid * 1024 + tid;
    long stride = (long)CVTX * 32 * 1024;
    for (long c = c0; c < CH_WD; c += stride) cvt_chunk(wd, wdb, (size_t)c << 3);
    return;
  }

  // XCD swizzle (by-major columns per XCD, proven)
  int lid = blockIdx.y * MAXTB + blockIdx.x;
  int sid = (lid & 7) * (MAXTB * 32 / 8) + (lid >> 3);
  int bx = sid % MAXTB;
  int by = sid / MAXTB;
  if (bx >= *ntb) return;
  int ent = tb[bx];
  int e = ent >> 16, rb = ent & 0xffff;
  int slotbase = offs[e] + rb * 256;
  int i0 = by * 128;

  int lane = tid & 63, w = tid >> 6;
  int wr = w >> 2, wc = w & 3;

  // staging lane constants (proven mapping)
  int cS = (lane & 7) ^ (lane >> 3);
  int rrS = 2 * (lane >> 3) + (cS >> 2);
  int kcS = (cS & 3) * 8;
  int tok = perm[slotbase + w * 16 + rrS]; if (tok < 0) tok = 0;
  const unsigned short* aptr = xb + (size_t)tok * D_ + kcS;
  const unsigned short* bptr = ((w & 1) ? wub : wgb)
      + ((size_t)e * I_ + i0 + (w >> 1) * 16 + rrS) * D_ + kcS;

  // read lane constants (proven mapping)
  int hl = (lane & 15) >> 1;
  int pA = (((lane & 1) * 4 + (lane >> 4)) ^ hl) * 8;
  int aOff = wr * 2048 + hl * 64 + pA;
  int bOff = wc * 2048 + hl * 64 + pA;

  f32x4 acc[4][4];
#pragma unroll
  for (int m = 0; m < 4; m++)
#pragma unroll
    for (int n = 0; n < 4; n++) acc[m][n] = f32x4{0.f,0.f,0.f,0.f};

  KLOOP32(64);   // D_/32

  // epilogue: n even = gate, n odd = up of icol group wc*2 + (n>>1)
#pragma unroll
  for (int m = 0; m < 4; m++) {
#pragma unroll
    for (int r = 0; r < 4; r++) {
      int row = wr * 64 + m * 16 + (lane >> 4) * 4 + r;
      size_t hbase = (size_t)(slotbase + row) * I_ + i0 + (lane & 15);
#pragma unroll
      for (int pr = 0; pr < 2; pr++) {
        float g = acc[m][pr*2][r];
        float u = acc[m][pr*2+1][r];
        float h = (g / (1.0f + __expf(-g))) * u;
        H[hbase + (2 * wc + pr) * 16] = f2bf(h);
      }
    }
  }
}

// ---------------- down: 256 slots x 256 D-cols, weighted atomic scatter (r12) ----------------
__global__ __launch_bounds__(1024, 4)
void down32_kernel(const unsigned short* __restrict__ H,
                   const unsigned short* __restrict__ wdb,
                   const int* __restrict__ tb, const int* __restrict__ ntb,
                   const int* __restrict__ offs, const int* __restrict__ perm,
                   const float* __restrict__ wgt,
                   float* __restrict__ out)
{
  __shared__ unsigned short smem[32768];

  int tid = threadIdx.x;
  int lid = blockIdx.y * MAXTB + blockIdx.x;
  int sid = (lid & 7) * (MAXTB * 8 / 8) + (lid >> 3);
  int bx = sid % MAXTB;
  int by = sid / MAXTB;
  if (bx >= *ntb) return;
  int ent = tb[bx];
  int e = ent >> 16, rb = ent & 0xffff;
  int slotbase = offs[e] + rb * 256;
  int d0 = by * 256;

  int lane = tid & 63, w = tid >> 6;
  int wr = w >> 2, wc = w & 3;

  int cS = (lane & 7) ^ (lane >> 3);
  int rrS = 2 * (lane >> 3) + (cS >> 2);
  int kcS = (cS & 3) * 8;
  const unsigned short* aptr = H + (size_t)(slotbase + w * 16 + rrS) * I_ + kcS;
  const unsigned short* bptr = wdb + ((size_t)e * D_ + d0 + w * 16 + rrS) * I_ + kcS;

  int hl = (lane & 15) >> 1;
  int pA = (((lane & 1) * 4 + (lane >> 4)) ^ hl) * 8;
  int aOff = wr * 2048 + hl * 64 + pA;
  int bOff = wc * 2048 + hl * 64 + pA;

  f32x4 acc[4][4];
#pragma unroll
  for (int m = 0; m < 4; m++)
#pragma unroll
    for (int n = 0; n < 4; n++) acc[m][n] = f32x4{0.f,0.f,0.f,0.f};

  KLOOP32(128);  // I_/32

#pragma unroll
  for (int m = 0; m < 4; m++) {
#pragma unroll
    for (int r = 0; r < 4; r++) {
      int row = wr * 64 + m * 16 + (lane >> 4) * 4 + r;
      int s = slotbase + row;
      int tok = perm[s];
      if (tok < 0) continue;
      float wv = wgt[s];
      float* op = out + (size_t)tok * D_ + d0 + wc * 64 + (lane & 15);
#pragma unroll
      for (int n = 0; n < 4; n++)
        atomicAdd(op + n * 16, acc[m][n][r] * wv);
    }
  }
}

extern "C" void kernel_launch(void* const* d_in, const int* in_sizes, int n_in,
                              void* d_out, int out_size, void* d_ws, size_t ws_size,
                              hipStream_t stream)
{
  const float* x  = (const float*)d_in[0];
  const float* ew = (const float*)d_in[1];
  const int*  idx = (const int*)d_in[2];
  const float* wg = (const float*)d_in[4];
  const float* wu = (const float*)d_in[5];
  const float* wd = (const float*)d_in[6];
  float* out = (float*)d_out;

  char* ws = (char*)d_ws;
  int* cnt   = (int*)(ws);
  int* ntb   = (int*)(ws + 64);
  int* tb    = (int*)(ws + 128);
  int* offs  = (int*)(ws + 640);
  int* perm  = (int*)(ws + 4096);
  float* wgt = (float*)(ws + 4096 + PADMAX * 4);

  const size_t xb_off = 131072;
  const size_t xb_b   = (size_t)N_ * D_ * 2;         // 16.78 MB
  const size_t H_b    = (size_t)PADMAX * I_ * 2;     // 83.9 MB
  const size_t w_b    = (size_t)E_ * I_ * D_ * 2;    // 134.2 MB each
  unsigned short* xb  = (unsigned short*)(ws + xb_off);
  unsigned short* H   = (unsigned short*)(ws + xb_off + xb_b);
  unsigned short* wgb = (unsigned short*)(ws + xb_off + xb_b + H_b);
  unsigned short* wub = (unsigned short*)((char*)wgb + w_b);
  unsigned short* wdb = (unsigned short*)((char*)wub + w_b);

  hipMemsetAsync(d_out, 0, (size_t)N_ * D_ * sizeof(float), stream);
  // K1: route + x cvt + FULL wg/wu cvt (streaming ~1.1 GB)
  head_kernel<<<2048, 512, 0, stream>>>(idx, ew, cnt, offs, tb, ntb, perm, wgt,
                                        x, xb, wg, wgb, wu, wub);
  // K2: merged full-I gate/up GEMM + fine-grained wd cvt columns
  gu32_kernel<<<dim3(MAXTB + CVTX, 32), 1024, 0, stream>>>(
      xb, wgb, wub, tb, ntb, offs, perm, H, wd, wdb);
  // K3: down GEMM (40 x 8 = 320 blocks)
  down32_kernel<<<dim3(MAXTB, 8), 1024, 0, stream>>>(
      H, wdb, tb, ntb, offs, perm, wgt, out);
}

// Round 14
// 804.286 us; speedup vs baseline: 1.1526x; 1.1526x over previous
//
#include <hip/hip_runtime.h>
#include <hip/hip_bf16.h>
#include <math.h>

// Problem constants
#define E_ 8
#define D_ 2048
#define I_ 4096
#define TOPK_ 2
#define N_ 4096
#define NPAIR (N_*TOPK_)
#define PADMAX 10240
#define MAXTB 40
#define CVTX 12          // converter bx columns in K2/K3
#define CH_X   (1L<<20)  // x chunks (8 elems each)
#define CH_HALF (1L<<22) // per-matrix half-I chunks
#define CH_WD  (1L<<23)  // full wd chunks

typedef __attribute__((ext_vector_type(8))) short s8v;
typedef __attribute__((ext_vector_type(8))) unsigned short us8;
typedef __attribute__((ext_vector_type(4))) float f32x4;
typedef const __attribute__((address_space(1))) void* gvp;
typedef __attribute__((address_space(3))) void* lvp;

__device__ __forceinline__ unsigned short f2bf(float f) {
  union { float f; unsigned int u; } c; c.f = f;
  unsigned int u = c.u;
  u += 0x7fffu + ((u >> 16) & 1u);
  return (unsigned short)(u >> 16);
}

__device__ __forceinline__ void cvt_chunk(const float* __restrict__ src,
                                          unsigned short* __restrict__ dst,
                                          size_t off) {
  float4 a = *(const float4*)(src + off);
  float4 b = *(const float4*)(src + off + 4);
  us8 o;
  o[0]=f2bf(a.x); o[1]=f2bf(a.y); o[2]=f2bf(a.z); o[3]=f2bf(a.w);
  o[4]=f2bf(b.x); o[5]=f2bf(b.y); o[6]=f2bf(b.z); o[7]=f2bf(b.w);
  *(us8*)(dst + off) = o;
}

// convert chunk of an I-half region of a [E][I][D] matrix (ihalf = 0/1)
__device__ __forceinline__ void cvt_half(const float* __restrict__ src,
                                         unsigned short* __restrict__ dst,
                                         long chunk, int ihalf) {
  long f = chunk << 3;
  int e = (int)(f >> 22);
  long r = f & ((1L << 22) - 1);
  size_t off = ((size_t)e << 23) + ((size_t)ihalf << 22) + (size_t)r;
  cvt_chunk(src, dst, off);
}

// ---------------- Head: route (block 0) + x cvt + wg/wu half0 cvt ----------------
__global__ __launch_bounds__(512)
void head_kernel(const int* __restrict__ idx, const float* __restrict__ ew,
                 int* cnt, int* offs, int* tb, int* ntb,
                 int* perm, float* wgt,
                 const float* __restrict__ x, unsigned short* __restrict__ xb,
                 const float* __restrict__ wg, unsigned short* __restrict__ wgb,
                 const float* __restrict__ wu, unsigned short* __restrict__ wub)
{
  if (blockIdx.x == 0) {
    __shared__ int scnt[E_], soff[E_ + 1], scur[E_];
    int t = threadIdx.x;
    if (t < E_) scnt[t] = 0;
    __syncthreads();
    for (int p = t; p < NPAIR; p += blockDim.x) atomicAdd(&scnt[idx[p]], 1);
    __syncthreads();
    if (t == 0) {
      int o = 0;
      for (int e = 0; e < E_; e++) {
        soff[e] = o; scur[e] = o;
        o += ((scnt[e] + 255) / 256) * 256;
      }
      soff[E_] = o;
      int T = 0;
      for (int e = 0; e < E_; e++) {
        int nb = (scnt[e] + 255) / 256;
        for (int rb = 0; rb < nb; rb++) tb[T++] = (e << 16) | rb;
      }
      *ntb = T;
      for (int e = 0; e < E_; e++) { cnt[e] = scnt[e]; offs[e] = soff[e]; }
      offs[E_] = o;
    }
    __syncthreads();
    for (int e = 0; e < E_; e++) {
      int start = soff[e] + scnt[e], end = soff[e + 1];
      for (int s = start + t; s < end; s += blockDim.x) { perm[s] = -1; wgt[s] = 0.f; }
    }
    __syncthreads();
    for (int p = t; p < NPAIR; p += blockDim.x) {
      int e = idx[p];
      int pos = atomicAdd(&scur[e], 1);
      perm[pos] = p / TOPK_;
      wgt[pos]  = ew[p];
    }
    return;
  }
  const long TOTAL = CH_X + 2 * CH_HALF;
  long c0 = (long)(blockIdx.x - 1) * 512 + threadIdx.x;
  long stride = (long)(gridDim.x - 1) * 512;
  for (long c = c0; c < TOTAL; c += stride) {
    if (c < CH_X) cvt_chunk(x, xb, (size_t)c << 3);
    else if (c < CH_X + CH_HALF) cvt_half(wg, wgb, c - CH_X, 0);
    else cvt_half(wu, wub, c - CH_X - CH_HALF, 0);
  }
}

// =================== BK=32, 16-wave, 64 KB LDS, double-buffered GEMM (r12 proven) ===================
// Slab layout = round-3 proven (0 conflicts): [128 vrow][64 ushort]; vrow v packs
// rows 2v,2v+1; chunk c=(r&1)*4+kc at position p = c ^ (v&7). Stage: wave w ->
// vrows w*8..w*8+7 (dest w*512); source row = w*16+rrS, k = kcS with
// cS=(lane&7)^(lane>>3), rrS=2*(lane>>3)+(cS>>2), kcS=(cS&3)*8. Read:
// hl=(lane&15)>>1, pA=(((lane&1)*4+(lane>>4))^hl)*8, off = base + m*512 + hl*64 + pA.
// Pipeline: dbuf, VMW(2) before start-barrier (VMW(0) last), STG(t+2) after
// end-barrier; raw s_barrier only.

#define SB  __builtin_amdgcn_sched_barrier(0)
#define BARR __builtin_amdgcn_s_barrier()
#define VMW(N) asm volatile("s_waitcnt vmcnt(" #N ")" ::: "memory")
#define PRIO1 __builtin_amdgcn_s_setprio(1)
#define PRIO0 __builtin_amdgcn_s_setprio(0)

#define STG(T,P) { \
  __builtin_amdgcn_global_load_lds((gvp)(aptr + (size_t)(T)*32), (lvp)(&smem[(P)*8192 + w*512]), 16, 0, 0); \
  __builtin_amdgcn_global_load_lds((gvp)(bptr + (size_t)(T)*32), (lvp)(&smem[16384 + (P)*8192 + w*512]), 16, 0, 0); }

#define TILE32(T,P,NT_) { \
  if ((T) == (NT_)-1) { VMW(0); } else { VMW(2); } \
  SB; BARR; SB; \
  { const unsigned short* ap_ = &smem[(P)*8192 + aOff]; \
    const unsigned short* bp_ = &smem[16384 + (P)*8192 + bOff]; \
    s8v af[4], bf[4]; \
    af[0]=*(const s8v*)(ap_);      af[1]=*(const s8v*)(ap_+512); \
    af[2]=*(const s8v*)(ap_+1024); af[3]=*(const s8v*)(ap_+1536); \
    bf[0]=*(const s8v*)(bp_);      bf[1]=*(const s8v*)(bp_+512); \
    bf[2]=*(const s8v*)(bp_+1024); bf[3]=*(const s8v*)(bp_+1536); \
    PRIO1; \
    _Pragma("unroll") for (int m_=0;m_<4;m_++) \
      _Pragma("unroll") for (int n_=0;n_<4;n_++) \
        acc[m_][n_] = __builtin_amdgcn_mfma_f32_16x16x32_bf16(af[m_], bf[n_], acc[m_][n_], 0,0,0); \
    PRIO0; } \
  SB; BARR; SB; \
  if ((T)+2 < (NT_)) { STG((T)+2, P); } }

#define KLOOP32(NT_) { \
  STG(0,0); STG(1,1); \
  _Pragma("unroll 1") for (int tt=0; tt<(NT_)/2; ++tt) { \
    TILE32(2*tt,   0, NT_); \
    TILE32(2*tt+1, 1, NT_); } }

// ---------------- gate+up: 256 tokens x 256 vcols (128 icols x {g,u}) ----------------
// Wave parity selects gate/up (V bit4 = w&1); read frag n parity = gate/up.
__global__ __launch_bounds__(1024, 4)
void gu32_kernel(const unsigned short* __restrict__ xb,
                 const unsigned short* __restrict__ wgb,
                 const unsigned short* __restrict__ wub,
                 const int* __restrict__ tb, const int* __restrict__ ntb,
                 const int* __restrict__ offs, const int* __restrict__ perm,
                 unsigned short* __restrict__ H,
                 int i_base, int cvt_mode,
                 const float* __restrict__ cs0, unsigned short* __restrict__ cd0,
                 const float* __restrict__ cs1, unsigned short* __restrict__ cd1)
{
  __shared__ unsigned short smem[32768];   // 64 KB

  int tid = threadIdx.x;
  if (blockIdx.x >= MAXTB) {
    long cid = (long)(blockIdx.x - MAXTB) + (long)CVTX * blockIdx.y;
    long c0 = cid * 1024 + tid;
    long stride = (long)CVTX * 16 * 1024;
    if (cvt_mode == 1) {
      for (long c = c0; c < 2 * CH_HALF; c += stride) {
        if (c < CH_HALF) cvt_half(cs0, cd0, c, 1);
        else cvt_half(cs1, cd1, c - CH_HALF, 1);
      }
    } else if (cvt_mode == 2) {
      for (long c = c0; c < CH_WD; c += stride) cvt_chunk(cs0, cd0, (size_t)c << 3);
    }
    return;
  }

  // XCD swizzle (by-major columns per XCD, proven round-3)
  int lid = blockIdx.y * MAXTB + blockIdx.x;
  int sid = (lid & 7) * (MAXTB * 16 / 8) + (lid >> 3);
  int bx = sid % MAXTB;
  int by = sid / MAXTB;
  if (bx >= *ntb) return;
  int ent = tb[bx];
  int e = ent >> 16, rb = ent & 0xffff;
  int slotbase = offs[e] + rb * 256;
  int i0 = i_base + by * 128;

  int lane = tid & 63, w = tid >> 6;
  int wr = w >> 2, wc = w & 3;

  // staging lane constants (proven round-3 mapping)
  int cS = (lane & 7) ^ (lane >> 3);
  int rrS = 2 * (lane >> 3) + (cS >> 2);
  int kcS = (cS & 3) * 8;
  int tok = perm[slotbase + w * 16 + rrS]; if (tok < 0) tok = 0;
  const unsigned short* aptr = xb + (size_t)tok * D_ + kcS;
  const unsigned short* bptr = ((w & 1) ? wub : wgb)
      + ((size_t)e * I_ + i0 + (w >> 1) * 16 + rrS) * D_ + kcS;

  // read lane constants (proven round-3 mapping)
  int hl = (lane & 15) >> 1;
  int pA = (((lane & 1) * 4 + (lane >> 4)) ^ hl) * 8;
  int aOff = wr * 2048 + hl * 64 + pA;
  int bOff = wc * 2048 + hl * 64 + pA;

  f32x4 acc[4][4];
#pragma unroll
  for (int m = 0; m < 4; m++)
#pragma unroll
    for (int n = 0; n < 4; n++) acc[m][n] = f32x4{0.f,0.f,0.f,0.f};

  KLOOP32(64);   // D_/32

  // epilogue: n even = gate, n odd = up of icol group wc*2 + (n>>1)
#pragma unroll
  for (int m = 0; m < 4; m++) {
#pragma unroll
    for (int r = 0; r < 4; r++) {
      int row = wr * 64 + m * 16 + (lane >> 4) * 4 + r;
      size_t hbase = (size_t)(slotbase + row) * I_ + i0 + (lane & 15);
#pragma unroll
      for (int pr = 0; pr < 2; pr++) {
        float g = acc[m][pr*2][r];
        float u = acc[m][pr*2+1][r];
        float h = (g / (1.0f + __expf(-g))) * u;
        H[hbase + (2 * wc + pr) * 16] = f2bf(h);
      }
    }
  }
}

// ---------------- down: 256 slots x 256 D-cols, K-split z=2, weighted atomic scatter ----------------
__global__ __launch_bounds__(1024, 4)
void down32_kernel(const unsigned short* __restrict__ H,
                   const unsigned short* __restrict__ wdb,
                   const int* __restrict__ tb, const int* __restrict__ ntb,
                   const int* __restrict__ offs, const int* __restrict__ perm,
                   const float* __restrict__ wgt,
                   float* __restrict__ out)
{
  __shared__ unsigned short smem[32768];

  int tid = threadIdx.x;
  // grid 40 x 8 x 2 = 640 blocks; by-major swizzle: each XCD gets 2 (by,z) cols x all bx
  int lid = (blockIdx.z * gridDim.y + blockIdx.y) * gridDim.x + blockIdx.x;
  int sid = (lid & 7) * 80 + (lid >> 3);
  int bx = sid % MAXTB;
  int rem = sid / MAXTB;
  int by = rem & 7;
  int z  = rem >> 3;
  if (bx >= *ntb) return;
  int ent = tb[bx];
  int e = ent >> 16, rb = ent & 0xffff;
  int slotbase = offs[e] + rb * 256;
  int d0 = by * 256;
  int kb = z * (I_ / 2);

  int lane = tid & 63, w = tid >> 6;
  int wr = w >> 2, wc = w & 3;

  int cS = (lane & 7) ^ (lane >> 3);
  int rrS = 2 * (lane >> 3) + (cS >> 2);
  int kcS = (cS & 3) * 8;
  const unsigned short* aptr = H + (size_t)(slotbase + w * 16 + rrS) * I_ + kcS + kb;
  const unsigned short* bptr = wdb + ((size_t)e * D_ + d0 + w * 16 + rrS) * I_ + kcS + kb;

  int hl = (lane & 15) >> 1;
  int pA = (((lane & 1) * 4 + (lane >> 4)) ^ hl) * 8;
  int aOff = wr * 2048 + hl * 64 + pA;
  int bOff = wc * 2048 + hl * 64 + pA;

  f32x4 acc[4][4];
#pragma unroll
  for (int m = 0; m < 4; m++)
#pragma unroll
    for (int n = 0; n < 4; n++) acc[m][n] = f32x4{0.f,0.f,0.f,0.f};

  KLOOP32(64);   // (I_/2)/32

#pragma unroll
  for (int m = 0; m < 4; m++) {
#pragma unroll
    for (int r = 0; r < 4; r++) {
      int row = wr * 64 + m * 16 + (lane >> 4) * 4 + r;
      int s = slotbase + row;
      int tok = perm[s];
      if (tok < 0) continue;
      float wv = wgt[s];
      float* op = out + (size_t)tok * D_ + d0 + wc * 64 + (lane & 15);
#pragma unroll
      for (int n = 0; n < 4; n++)
        atomicAdd(op + n * 16, acc[m][n][r] * wv);
    }
  }
}

extern "C" void kernel_launch(void* const* d_in, const int* in_sizes, int n_in,
                              void* d_out, int out_size, void* d_ws, size_t ws_size,
                              hipStream_t stream)
{
  const float* x  = (const float*)d_in[0];
  const float* ew = (const float*)d_in[1];
  const int*  idx = (const int*)d_in[2];
  const float* wg = (const float*)d_in[4];
  const float* wu = (const float*)d_in[5];
  const float* wd = (const float*)d_in[6];
  float* out = (float*)d_out;

  char* ws = (char*)d_ws;
  int* cnt   = (int*)(ws);
  int* ntb   = (int*)(ws + 64);
  int* tb    = (int*)(ws + 128);
  int* offs  = (int*)(ws + 640);
  int* perm  = (int*)(ws + 4096);
  float* wgt = (float*)(ws + 4096 + PADMAX * 4);

  const size_t xb_off = 131072;
  const size_t xb_b   = (size_t)N_ * D_ * 2;         // 16.78 MB
  const size_t H_b    = (size_t)PADMAX * I_ * 2;     // 83.9 MB
  const size_t w_b    = (size_t)E_ * I_ * D_ * 2;    // 134.2 MB each
  unsigned short* xb  = (unsigned short*)(ws + xb_off);
  unsigned short* H   = (unsigned short*)(ws + xb_off + xb_b);
  unsigned short* wgb = (unsigned short*)(ws + xb_off + xb_b + H_b);
  unsigned short* wub = (unsigned short*)((char*)wgb + w_b);
  unsigned short* wdb = (unsigned short*)((char*)wub + w_b);

  hipMemsetAsync(d_out, 0, (size_t)N_ * D_ * sizeof(float), stream);
  // K1: route + x cvt + wg/wu half0 cvt
  head_kernel<<<2048, 512, 0, stream>>>(idx, ew, cnt, offs, tb, ntb, perm, wgt,
                                        x, xb, wg, wgb, wu, wub);
  // K2: gate/up GEMM on I-half0, converts wg/wu half1
  gu32_kernel<<<dim3(MAXTB + CVTX, 16), 1024, 0, stream>>>(
      xb, wgb, wub, tb, ntb, offs, perm, H, 0, 1, wg, wgb, wu, wub);
  // K3: gate/up GEMM on I-half1, converts wd
  gu32_kernel<<<dim3(MAXTB + CVTX, 16), 1024, 0, stream>>>(
      xb, wgb, wub, tb, ntb, offs, perm, H, I_ / 2, 2, wd, wdb,
      (const float*)0, (unsigned short*)0);
  // K4: down GEMM, K-split z=2 (40 x 8 x 2 = 640 blocks)
  down32_kernel<<<dim3(MAXTB, 8, 2), 1024, 0, stream>>>(
      H, wdb, tb, ntb, offs, perm, wgt, out);
}